// Round 3
// baseline (8095.514 us; speedup 1.0000x reference)
//
#include <hip/hip_runtime.h>
#include <cstdint>
#include <cstddef>

#define P 16384      // H*W
#define CDIM 768
typedef unsigned short ushort_t;

__device__ __forceinline__ float bf2f(unsigned int u) { return __uint_as_float(u << 16); }
__device__ __forceinline__ ushort_t f2bf(float f) {
  unsigned int x = __float_as_uint(f);
  x = (x + 0x7fffu + ((x >> 16) & 1u)) >> 16;   // round-to-nearest-even
  return (ushort_t)x;
}

// ---------------- rms_in scale: w[c] / (std_ddof1 + eps) per (b,c) plane ----------------
template<typename T>
__global__ __launch_bounds__(256) void rms_stats_k(
    const T* __restrict__ x, const float* __restrict__ w,
    float* __restrict__ scale, float eps)
{
  int bc = blockIdx.x;                       // b*CDIM + c, 1536 blocks
  float s = 0.f, ss = 0.f;
  if constexpr (sizeof(T) == 4) {
    const float4* p = (const float4*)((const float*)x + (size_t)bc * P);
    for (int i = threadIdx.x; i < P / 4; i += 256) {
      float4 v = p[i];
      s  += v.x + v.y + v.z + v.w;
      ss += v.x * v.x + v.y * v.y + v.z * v.z + v.w * v.w;
    }
  } else {
    const uint4* p = (const uint4*)((const ushort_t*)x + (size_t)bc * P);
    for (int i = threadIdx.x; i < P / 8; i += 256) {
      uint4 v = p[i];
      float f0 = bf2f(v.x & 0xffffu), f1 = bf2f(v.x >> 16);
      float f2 = bf2f(v.y & 0xffffu), f3 = bf2f(v.y >> 16);
      float f4v = bf2f(v.z & 0xffffu), f5 = bf2f(v.z >> 16);
      float f6 = bf2f(v.w & 0xffffu), f7 = bf2f(v.w >> 16);
      s  += ((f0 + f1) + (f2 + f3)) + ((f4v + f5) + (f6 + f7));
      ss += ((f0*f0 + f1*f1) + (f2*f2 + f3*f3)) + ((f4v*f4v + f5*f5) + (f6*f6 + f7*f7));
    }
  }
  #pragma unroll
  for (int off = 32; off > 0; off >>= 1) {
    s  += __shfl_down(s, off);
    ss += __shfl_down(ss, off);
  }
  __shared__ float rs[4], rss[4];
  int wid = threadIdx.x >> 6;
  if ((threadIdx.x & 63) == 0) { rs[wid] = s; rss[wid] = ss; }
  __syncthreads();
  if (threadIdx.x == 0) {
    s = rs[0] + rs[1] + rs[2] + rs[3];
    ss = rss[0] + rss[1] + rss[2] + rss[3];
    const float n = (float)P;
    float var = fmaxf((ss - s * s / n) / (n - 1.f), 0.f);   // ddof=1
    scale[bc] = w[bc % CDIM] / (sqrtf(var) + eps);
  }
}

// ---------------- generic tiled GEMM: out[b] = A(MxK) * (scaleB .* B[b](K x Ncols)) ----------------
// EPI: 0 = +bias; 1 = (+bias)*gamma + resid (x2 path); 2 = gelu(+bias) (fc1)
// BBF16: B matrix stored bf16.  OBF16: output stored bf16.
// ldB/ldO: row strides (elements). strideB/strideO/strideR: per-batch strides (elements).
// resid row stride fixed = P.
template<int BBF16, int EPI, int OBF16>
__global__ __launch_bounds__(256) void gemm_k(
    const float* __restrict__ A, const void* __restrict__ Bmv,
    const float* __restrict__ bias, const float* __restrict__ scaleB,
    const float* __restrict__ gamma, const float* __restrict__ resid,
    void* __restrict__ outv,
    int K, size_t ldB, size_t ldO, size_t strideB, size_t strideO, size_t strideR)
{
  int b  = blockIdx.z;
  int n0 = blockIdx.x * 128;
  int m0 = blockIdx.y * 128;
  __shared__ float As[16][132];   // transposed A tile, +4 pad
  __shared__ float Bs[16][128];
  int t = threadIdx.x;
  int tm = t >> 4, tn = t & 15;
  float acc[8][8];
  #pragma unroll
  for (int i = 0; i < 8; ++i) {
    #pragma unroll
    for (int j = 0; j < 8; ++j) acc[i][j] = 0.f;
  }
  const float* sp = scaleB ? scaleB + (size_t)b * CDIM : nullptr;

  for (int k0 = 0; k0 < K; k0 += 16) {
    __syncthreads();
    // stage A 128x16 (transposed into LDS)
    #pragma unroll
    for (int l = 0; l < 2; ++l) {
      int f4 = t + l * 256;
      int i = f4 >> 2, j = (f4 & 3) << 2;
      float4 v = *(const float4*)(A + (size_t)(m0 + i) * K + k0 + j);
      As[j + 0][i] = v.x; As[j + 1][i] = v.y; As[j + 2][i] = v.z; As[j + 3][i] = v.w;
    }
    // stage B 16x128 (fused per-K-channel scale = rms_in)
    if constexpr (BBF16) {
      const ushort_t* Bp = (const ushort_t*)Bmv + (size_t)b * strideB;
      int r = t >> 4, c = (t & 15) << 3;
      uint4 raw = *(const uint4*)(Bp + (size_t)(k0 + r) * ldB + n0 + c);
      float scv = sp ? sp[k0 + r] : 1.f;
      Bs[r][c + 0] = bf2f(raw.x & 0xffffu) * scv; Bs[r][c + 1] = bf2f(raw.x >> 16) * scv;
      Bs[r][c + 2] = bf2f(raw.y & 0xffffu) * scv; Bs[r][c + 3] = bf2f(raw.y >> 16) * scv;
      Bs[r][c + 4] = bf2f(raw.z & 0xffffu) * scv; Bs[r][c + 5] = bf2f(raw.z >> 16) * scv;
      Bs[r][c + 6] = bf2f(raw.w & 0xffffu) * scv; Bs[r][c + 7] = bf2f(raw.w >> 16) * scv;
    } else {
      const float* Bp = (const float*)Bmv + (size_t)b * strideB;
      #pragma unroll
      for (int l = 0; l < 2; ++l) {
        int f4 = t + l * 256;
        int r = f4 >> 5, c = (f4 & 31) << 2;
        float4 v = *(const float4*)(Bp + (size_t)(k0 + r) * ldB + n0 + c);
        float scv = sp ? sp[k0 + r] : 1.f;
        v.x *= scv; v.y *= scv; v.z *= scv; v.w *= scv;
        *(float4*)&Bs[r][c] = v;
      }
    }
    __syncthreads();
    #pragma unroll
    for (int kk = 0; kk < 16; ++kk) {
      float a_[8], b_[8];
      *(float4*)&a_[0] = *(const float4*)&As[kk][tm * 8];
      *(float4*)&a_[4] = *(const float4*)&As[kk][tm * 8 + 4];
      *(float4*)&b_[0] = *(const float4*)&Bs[kk][tn * 8];
      *(float4*)&b_[4] = *(const float4*)&Bs[kk][tn * 8 + 4];
      #pragma unroll
      for (int i = 0; i < 8; ++i) {
        #pragma unroll
        for (int j = 0; j < 8; ++j) acc[i][j] = fmaf(a_[i], b_[j], acc[i][j]);
      }
    }
  }

  int row0 = m0 + tm * 8, col = n0 + tn * 8;
  #pragma unroll
  for (int i = 0; i < 8; ++i) {
    int mi = row0 + i;
    float bb = bias[mi];
    float r[8];
    #pragma unroll
    for (int j = 0; j < 8; ++j) r[j] = acc[i][j] + bb;
    if constexpr (EPI == 1) {
      float g = gamma[mi];
      const float* rp = resid + (size_t)b * strideR + (size_t)mi * P + col;
      float4 r0 = *(const float4*)rp, r1 = *(const float4*)(rp + 4);
      r[0] = r[0] * g + r0.x; r[1] = r[1] * g + r0.y; r[2] = r[2] * g + r0.z; r[3] = r[3] * g + r0.w;
      r[4] = r[4] * g + r1.x; r[5] = r[5] * g + r1.y; r[6] = r[6] * g + r1.z; r[7] = r[7] * g + r1.w;
    }
    if constexpr (EPI == 2) {
      #pragma unroll
      for (int j = 0; j < 8; ++j) {
        float g = r[j];
        r[j] = 0.5f * g * (1.f + erff(g * 0.70710678118654752f));  // exact GELU
      }
    }
    if constexpr (OBF16) {
      ushort_t h[8];
      #pragma unroll
      for (int j = 0; j < 8; ++j) h[j] = f2bf(r[j]);
      uint4 pk;
      pk.x = h[0] | ((unsigned)h[1] << 16);
      pk.y = h[2] | ((unsigned)h[3] << 16);
      pk.z = h[4] | ((unsigned)h[5] << 16);
      pk.w = h[6] | ((unsigned)h[7] << 16);
      *(uint4*)((ushort_t*)outv + (size_t)b * strideO + (size_t)mi * ldO + col) = pk;
    } else {
      float* op = (float*)outv + (size_t)b * strideO + (size_t)mi * ldO + col;
      *(float4*)op       = make_float4(r[0], r[1], r[2], r[3]);
      *(float4*)(op + 4) = make_float4(r[4], r[5], r[6], r[7]);
    }
  }
}

// ---------------- LayerNorm of q,k over head dim (96), in place on bf16 qkv ----------------
__device__ __forceinline__ void ln_rows16(ushort_t* base, const float* w, const float* bv)
{
  float v[96];
  #pragma unroll
  for (int c = 0; c < 96; ++c) v[c] = bf2f(base[(size_t)c * P]);
  float mu = 0.f;
  #pragma unroll
  for (int c = 0; c < 96; ++c) mu += v[c];
  mu *= (1.f / 96.f);
  float var = 0.f;
  #pragma unroll
  for (int c = 0; c < 96; ++c) { float d = v[c] - mu; var += d * d; }
  var *= (1.f / 96.f);                        // ddof=0
  float inv = rsqrtf(var + 1e-5f);
  #pragma unroll
  for (int c = 0; c < 96; ++c)
    base[(size_t)c * P] = f2bf((v[c] - mu) * inv * w[c] + bv[c]);
}

__global__ __launch_bounds__(256) void ln_qk_k(ushort_t* __restrict__ qkv,
    const float* __restrict__ qw, const float* __restrict__ qb,
    const float* __restrict__ kw, const float* __restrict__ kb)
{
  size_t tid = (size_t)blockIdx.x * 256 + threadIdx.x;   // B*NH*P = 262144
  int p = (int)(tid & (P - 1));
  int n = (int)((tid >> 14) & 7);
  int b = (int)(tid >> 17);
  ushort_t* base = qkv + ((size_t)b * 2304 + (size_t)n * 288) * P + p;
  ln_rows16(base, qw, qb);                    // q rows 0..95
  ln_rows16(base + (size_t)96 * P, kw, kb);   // k rows 96..191
}

// ---------------- axial attention, online softmax ----------------
// AXIS 0: along W (fixed h=line). AXIS 1: along H (fixed w=line).
// 256 thr: thread=(qi,ch) pair; each owns 48 of 96 channels; dot via shfl_xor(1).
template<int AXIS, int ACCUM>
__global__ __launch_bounds__(256) void attn_k(
    const ushort_t* __restrict__ qkv, ushort_t* __restrict__ a)
{
  int inst = blockIdx.x;
  int line = inst & 127;
  int n = (inst >> 7) & 7;
  int b = inst >> 10;
  const ushort_t* qb = qkv + ((size_t)b * 2304 + (size_t)n * 288) * P;
  const ushort_t* kb = qb + (size_t)96 * P;
  const ushort_t* vb = qb + (size_t)192 * P;
  int t = threadIdx.x, ch = t & 1, qi = t >> 1;
  __shared__ float Kl[64][104];   // stride 104: rows 16B-aligned; reads are broadcast
  __shared__ float Vl[64][104];   // total 53.25 KB -> 3 blocks/CU
  auto gpos = [&](int i) { return AXIS == 0 ? line * 128 + i : i * 128 + line; };

  float q[48], o[48];
  int cbase = ch * 48;
  #pragma unroll
  for (int j = 0; j < 48; ++j) q[j] = bf2f(qb[(size_t)(cbase + j) * P + gpos(qi)]);
  #pragma unroll
  for (int j = 0; j < 48; ++j) o[j] = 0.f;
  float mval = -1e30f, l = 0.f;
  const float sc = 0.10206207261596575f;   // 1/sqrt(96)

  for (int c0 = 0; c0 < 128; c0 += 64) {
    __syncthreads();
    {
      int ki = t & 63, half = t >> 6;
      #pragma unroll
      for (int i2 = 0; i2 < 24; ++i2) {
        int c = half + 4 * i2;
        int gp = gpos(c0 + ki);
        Kl[ki][c] = bf2f(kb[(size_t)c * P + gp]);
        Vl[ki][c] = bf2f(vb[(size_t)c * P + gp]);
      }
    }
    __syncthreads();
    for (int kk = 0; kk < 64; ++kk) {
      const float* kr = &Kl[kk][cbase];
      float s = 0.f;
      #pragma unroll
      for (int j = 0; j < 48; j += 4) {
        float4 kv = *(const float4*)(kr + j);
        s = fmaf(q[j], kv.x, s); s = fmaf(q[j + 1], kv.y, s);
        s = fmaf(q[j + 2], kv.z, s); s = fmaf(q[j + 3], kv.w, s);
      }
      s += __shfl_xor(s, 1);   // partner lane has the other 48 channels
      s *= sc;
      float nm = fmaxf(mval, s);
      float f  = __expf(mval - nm);
      float pe = __expf(s - nm);
      l = l * f + pe;
      mval = nm;
      const float* vr = &Vl[kk][cbase];
      #pragma unroll
      for (int j = 0; j < 48; j += 4) {
        float4 vv = *(const float4*)(vr + j);
        o[j]     = fmaf(pe, vv.x, o[j] * f);
        o[j + 1] = fmaf(pe, vv.y, o[j + 1] * f);
        o[j + 2] = fmaf(pe, vv.z, o[j + 2] * f);
        o[j + 3] = fmaf(pe, vv.w, o[j + 3] * f);
      }
    }
  }
  float invl = 0.5f / l;                     // fused 0.5*(xx+xy)
  size_t obase = ((size_t)b * CDIM + (size_t)(n * 96 + cbase)) * P + gpos(qi);
  #pragma unroll
  for (int j = 0; j < 48; ++j) {
    float val = o[j] * invl;
    size_t idx = obase + (size_t)j * P;
    if (ACCUM) a[idx] = f2bf(bf2f(a[idx]) + val);
    else       a[idx] = f2bf(val);
  }
}

// ---------------- final: out = x2 + gamma_mlp[c] * scale3[b,c] * m ----------------
__global__ __launch_bounds__(256) void final_k(
    const float* __restrict__ x2, const ushort_t* __restrict__ m,
    const float* __restrict__ scale3, const float* __restrict__ gmlp,
    float* __restrict__ out)
{
  const size_t total = (size_t)2 * CDIM * P / 8;      // 8 elements per iter
  for (size_t i = (size_t)blockIdx.x * 256 + threadIdx.x; i < total;
       i += (size_t)gridDim.x * 256) {
    size_t bc = i >> 11;                 // /(P/8)
    int c = (int)(bc % CDIM);
    float g = gmlp[c] * scale3[bc];
    float4 xa = ((const float4*)x2)[i * 2];
    float4 xb = ((const float4*)x2)[i * 2 + 1];
    uint4 mv = ((const uint4*)m)[i];
    float4 ra, rb;
    ra.x = xa.x + g * bf2f(mv.x & 0xffffu); ra.y = xa.y + g * bf2f(mv.x >> 16);
    ra.z = xa.z + g * bf2f(mv.y & 0xffffu); ra.w = xa.w + g * bf2f(mv.y >> 16);
    rb.x = xb.x + g * bf2f(mv.z & 0xffffu); rb.y = xb.y + g * bf2f(mv.z >> 16);
    rb.z = xb.z + g * bf2f(mv.w & 0xffffu); rb.w = xb.w + g * bf2f(mv.w >> 16);
    ((float4*)out)[i * 2]     = ra;
    ((float4*)out)[i * 2 + 1] = rb;
  }
}

extern "C" void kernel_launch(void* const* d_in, const int* in_sizes, int n_in,
                              void* d_out, int out_size, void* d_ws, size_t ws_size,
                              hipStream_t stream)
{
  const float* x    = (const float*)d_in[0];
  const float* n1w  = (const float*)d_in[1];
  const float* qkvw = (const float*)d_in[2];
  const float* qkvb = (const float*)d_in[3];
  const float* qnw  = (const float*)d_in[4];
  const float* qnb  = (const float*)d_in[5];
  const float* knw  = (const float*)d_in[6];
  const float* knb  = (const float*)d_in[7];
  const float* n2w  = (const float*)d_in[8];
  const float* outw = (const float*)d_in[9];
  const float* outb = (const float*)d_in[10];
  const float* gatt = (const float*)d_in[11];
  const float* fc1w = (const float*)d_in[12];
  const float* fc1b = (const float*)d_in[13];
  const float* fc2w = (const float*)d_in[14];
  const float* fc2b = (const float*)d_in[15];
  const float* mnw  = (const float*)d_in[16];
  const float* gmlp = (const float*)d_in[17];
  float* out = (float*)d_out;

  // ws pool, peak 192 MiB + 18 KiB (lifetime-disjoint overlaps):
  //   [0,144M)    qkv bf16            (dead after attention)
  //   [0,96M)     x2 fp32             (from out-proj; reuses qkv)
  //   [96M,144M)  hidden bf16 chunk   (reuses qkv)
  //   [144M,192M) a bf16 -> m bf16    (a dead after out-proj)
  //   [192M,+18K) scales
  char* ws = (char*)d_ws;
  ushort_t* qkv16  = (ushort_t*)ws;
  float*    x2     = (float*)ws;
  ushort_t* hid16  = (ushort_t*)(ws + 100663296);
  ushort_t* abuf16 = (ushort_t*)(ws + 150994944);
  ushort_t* mbuf16 = abuf16;
  float*    scale1 = (float*)(ws + 201326592);
  float*    scale2 = scale1 + 1536;
  float*    scale3 = scale2 + 1536;

  // 1) norm1 scales, fused into qkv GEMM's B operand
  rms_stats_k<float><<<1536, 256, 0, stream>>>(x, n1w, scale1, 1e-8f);
  // 2) qkv projection: [2304 x 768] * [768 x 16384] per batch -> bf16
  {
    dim3 g(128, 18, 2);
    gemm_k<0, 0, 1><<<g, 256, 0, stream>>>(qkvw, x, qkvb, scale1, nullptr, nullptr,
        qkv16, 768, P, P, (size_t)CDIM * P, (size_t)2304 * P, 0);
  }
  // 3) LN on q,k head channels (in-place bf16)
  ln_qk_k<<<1024, 256, 0, stream>>>(qkv16, qnw, qnb, knw, knb);
  // 4) axial attention: H-axis writes, W-axis accumulates
  attn_k<1, 0><<<2048, 256, 0, stream>>>(qkv16, abuf16);
  attn_k<0, 1><<<2048, 256, 0, stream>>>(qkv16, abuf16);
  // 5) norm2 scales + out-projection with gamma_att*(.)+x residual epilogue -> fp32 x2
  rms_stats_k<ushort_t><<<1536, 256, 0, stream>>>(abuf16, n2w, scale2, 1e-8f);
  {
    dim3 g(128, 6, 2);
    gemm_k<1, 1, 0><<<g, 256, 0, stream>>>(outw, abuf16, outb, scale2, gatt, x,
        x2, 768, P, P, (size_t)CDIM * P, (size_t)CDIM * P, (size_t)CDIM * P);
  }
  // 6) MLP chunked along N (4 x 4096 columns): fc1+GELU -> bf16 hidden; fc2 -> bf16 m
  for (int c = 0; c < 4; ++c) {
    const size_t coff = (size_t)c * 4096;
    dim3 g1(32, 24, 2);
    gemm_k<0, 2, 1><<<g1, 256, 0, stream>>>(fc1w, x2 + coff, fc1b, nullptr, nullptr, nullptr,
        hid16, 768, P, 4096, (size_t)CDIM * P, (size_t)3072 * 4096, 0);
    dim3 g2(32, 6, 2);
    gemm_k<1, 0, 1><<<g2, 256, 0, stream>>>(fc2w, hid16, fc2b, nullptr, nullptr, nullptr,
        mbuf16 + coff, 3072, 4096, P, (size_t)3072 * 4096, (size_t)CDIM * P, 0);
  }
  // 7) norm3 scales + final residual combine
  rms_stats_k<ushort_t><<<1536, 256, 0, stream>>>(mbuf16, mnw, scale3, 1e-8f);
  final_k<<<2048, 256, 0, stream>>>(x2, mbuf16, scale3, gmlp, out);

  (void)in_sizes; (void)n_in; (void)out_size; (void)ws_size;
}